// Round 4
// baseline (145.126 us; speedup 1.0000x reference)
//
#include <hip/hip_runtime.h>
#include <stdint.h>

typedef unsigned int u32;
typedef unsigned long long u64;
typedef _Float16 f16x8 __attribute__((ext_vector_type(8)));
typedef float f32x4 __attribute__((ext_vector_type(4)));

#define IJ 16384
#define NQ 1024
#define NB 2
#define KP 256
#define NSEG 16
#define SEGW 1024  // IJ / NSEG
#define NT 1024    // sampled rows (2 batches x 512)

// ---------------- Threefry-2x32 (JAX-compatible, 20 rounds) ----------------
__device__ __forceinline__ void tf2x32(u32 k0, u32 k1, u32& x0, u32& x1) {
  u32 kx = k0 ^ k1 ^ 0x1BD11BDAu;
#define TFR(r) { x0 += x1; x1 = (x1 << (r)) | (x1 >> (32 - (r))); x1 ^= x0; }
  x0 += k0; x1 += k1;
  TFR(13) TFR(15) TFR(26) TFR(6)
  x0 += k1; x1 += kx + 1u;
  TFR(17) TFR(29) TFR(16) TFR(24)
  x0 += kx; x1 += k0 + 2u;
  TFR(13) TFR(15) TFR(26) TFR(6)
  x0 += k0; x1 += k1 + 3u;
  TFR(17) TFR(29) TFR(16) TFR(24)
  x0 += k1; x1 += kx + 4u;
  TFR(13) TFR(15) TFR(26) TFR(6)
  x0 += kx; x1 += k0 + 5u;
#undef TFR
}

__device__ __forceinline__ void tf_subkey(u32 k0, u32 k1, u32 i, u32& s0, u32& s1) {
  u32 x0 = 0u, x1 = i;
  tf2x32(k0, k1, x0, x1);
  s0 = x0; s1 = x1;
}

__device__ __forceinline__ u32 tf_xorbits(u32 k0, u32 k1, u32 i) {
  u32 x0 = 0u, x1 = i;
  tf2x32(k0, k1, x0, x1);
  return x0 ^ x1;
}

__device__ __forceinline__ void derive_keys(int seed, u32& kq0, u32& kq1,
                                            u32& km0, u32& km1) {
  u32 k0 = 0u;
  u32 k1 = (u32)seed;
  tf_subkey(k0, k1, 0u, kq0, kq1);
  tf_subkey(k0, k1, 1u, km0, km1);
}

// n_idx[s] = random_bits(k2)[s] & 1023, k2 = split(kq)[1]
__device__ __forceinline__ int derive_n(int seed, u32 s) {
  u32 kq0, kq1, km0, km1;
  derive_keys(seed, kq0, kq1, km0, km1);
  u32 l0, l1;
  tf_subkey(kq0, kq1, 1u, l0, l1);
  return (int)(tf_xorbits(l0, l1, s) & 1023u);
}

__device__ __forceinline__ float gumbel_from_bits(u32 w) {
  const float tiny = 1.17549435e-38f;
  float fl = __uint_as_float((w >> 9) | 0x3f800000u) - 1.0f;
  float u = fl * (1.0f - tiny) + tiny;
  u = fmaxf(tiny, u);
  return -logf(-logf(u));
}

__device__ __forceinline__ bool read_bool(const void* p, int idx, int is32) {
  return is32 ? (((const int*)p)[idx] != 0)
              : (((const unsigned char*)p)[idx] != 0);
}

// monotone float<->u32 key (finite, non-NaN inputs)
__device__ __forceinline__ u32 fkey(float x) {
  u32 b = __float_as_uint(x);
  return b ^ ((b & 0x80000000u) ? 0xFFFFFFFFu : 0x80000000u);
}

// f32 -> (f16 hi, f16 lo*2^11) split, in-register
__device__ __forceinline__ void load_split(const float* __restrict__ src,
                                           f16x8& h1, f16x8& h2) {
  float4 a = *(const float4*)src;
  float4 b = *(const float4*)(src + 16);
  float x[8] = {a.x, a.y, a.z, a.w, b.x, b.y, b.z, b.w};
#pragma unroll
  for (int e = 0; e < 8; ++e) {
    _Float16 hi = (_Float16)x[e];
    h1[e] = hi;
    h2[e] = (_Float16)((x[e] - (float)hi) * 2048.0f);
  }
}

// fp32-emulated 16x16x32 via 4-MFMA Horner (error ~2^-21 per product)
__device__ __forceinline__ f32x4 emul_mfma(f16x8 m1, f16x8 m2, f16x8 q1,
                                           f16x8 q2) {
  const f32x4 zero4 = {0.f, 0.f, 0.f, 0.f};
  const float c11 = 4.8828125e-4f;  // 2^-11
  f32x4 x = __builtin_amdgcn_mfma_f32_16x16x32_f16(m2, q2, zero4, 0, 0, 0);
  x *= c11;
  x = __builtin_amdgcn_mfma_f32_16x16x32_f16(m2, q1, x, 0, 0, 0);
  x = __builtin_amdgcn_mfma_f32_16x16x32_f16(m1, q2, x, 0, 0, 0);
  x *= c11;
  return __builtin_amdgcn_mfma_f32_16x16x32_f16(m1, q1, x, 0, 0, 0);
}

// ---------------- K1: per-sampled-row chunk max + chunk sumexp -------------
// grid (64 ij-chunks, 16 row-groups); wave w owns rows [by*64+16w, +16).
// Blocks with (by&7)==0 also cache the f16 split of their f_map tiles to ws
// (read by K2 -> bit-identical values, no recompute). Block (0,0) side jobs:
// best[] init, bool-width detect, num_valid.
__global__ __launch_bounds__(256) void stats_kernel(
    const float* __restrict__ f_q, const float* __restrict__ f_map,
    const float* __restrict__ temp, const void* __restrict__ valid_q,
    const int* __restrict__ seedp, float* __restrict__ chunkmax,
    float* __restrict__ rowsum_part, u64* __restrict__ best,
    float* __restrict__ num_valid, int* __restrict__ bool_is32,
    _Float16* __restrict__ ms1, _Float16* __restrict__ ms2) {
  __shared__ int sred[256];
  __shared__ int is32_s;
  const int bx = blockIdx.x;  // 256-ij chunk
  const int by = blockIdx.y;  // 64-row group
  const int tid = threadIdx.x;
  const int w = tid >> 6, l = tid & 63, l15 = l & 15, g = l >> 4;
  const int b = by >> 3;
  const int tp = by * 64 + w * 16 + l15;
  const int n = derive_n(seedp[0], (u32)tp);
  f16x8 q1, q2;
  load_split(f_q + ((size_t)b * NQ + n) * 32 + g * 4, q1, q2);
  const float et = expf(temp[0]);
  const bool writer = ((by & 7) == 0);
  float rm = 0.f, se = 0.f;
#pragma unroll
  for (int T = 0; T < 16; ++T) {
    f16x8 m1, m2;
    load_split(f_map + ((size_t)b * IJ + (bx * 16 + T) * 16 + l15) * 32 + g * 4,
               m1, m2);
    if (writer) {  // cache split fragments for K2 (deterministic fn of f32)
      const size_t toff = ((size_t)(b * 1024 + bx * 16 + T) * 64 + l) * 8;
      *(f16x8*)(ms1 + toff) = m1;
      *(f16x8*)(ms2 + toff) = m2;
    }
    f32x4 r = emul_mfma(m1, m2, q1, q2);
#pragma unroll
    for (int j = 0; j < 4; ++j) {
      float v = fmaxf(r[j], 0.f) * et;
      rm = fmaxf(rm, v);
      se += __expf(v);  // s only enters v as per-row log-shift: fast exp safe
    }
  }
  // deterministic reduce over the 4 lanes (g=0..3) holding the same row
  se += __shfl_xor(se, 16, 64);
  rm = fmaxf(rm, __shfl_xor(rm, 16, 64));
  se += __shfl_xor(se, 32, 64);
  rm = fmaxf(rm, __shfl_xor(rm, 32, 64));
  if (g == 0) {
    chunkmax[(size_t)tp * 64 + bx] = rm;
    rowsum_part[(size_t)tp * 64 + bx] = se;
  }
  if (bx == 0 && by == 0) {  // uniform per block: side jobs
    __syncthreads();
    for (int i = tid; i < NT; i += 256) best[i] = 0ull;  // fkey(-inf) floor
    const unsigned char* vb = (const unsigned char*)valid_q;
    int ones = 0;
    for (int i = tid; i < 2048; i += 256) ones += (vb[i] == 1) ? 1 : 0;
    sred[tid] = ones;
    __syncthreads();
    for (int off = 128; off > 0; off >>= 1) {
      if (tid < off) sred[tid] += sred[tid + off];
      __syncthreads();
    }
    if (tid == 0) {
      is32_s = (sred[0] < 1152) ? 1 : 0;
      bool_is32[0] = is32_s;
    }
    __syncthreads();
    const int is32 = is32_s;
    for (int bb = 0; bb < 2; ++bb) {
      int acc = 0;
      for (int i = tid; i < NQ; i += 256)
        acc += read_bool(valid_q, bb * NQ + i, is32) ? 1 : 0;
      sred[tid] = acc;
      __syncthreads();
      for (int off = 128; off > 0; off >>= 1) {
        if (tid < off) sred[tid] += sred[tid + off];
        __syncthreads();
      }
      if (tid == 0) {
        float nv = (float)sred[0];
        num_valid[bb] = nv < 1.f ? 1.f : nv;
      }
      __syncthreads();
    }
  }
}

// ---------------- K2: recompute + categorical argmax -----------------------
// Block = 16 sampled rows x SEGW ij. Reads the cached f16 fragments (bitwise
// == K1's split) -> sim recompute bit-identical. mrow/srow reduced in fixed
// order. Candidates (val > m-22; winner bound m-21.11) compacted with
// wave-aggregated ballot; exact R7 v; (max v, min f) via guarded packed u64
// atomicMax (order-independent lattice).
__global__ __launch_bounds__(256) void select_kernel(
    const _Float16* __restrict__ ms1, const _Float16* __restrict__ ms2,
    const float* __restrict__ f_q, const float* __restrict__ temp,
    const float* __restrict__ chunkmax, const float* __restrict__ rowsum_part,
    const float* __restrict__ num_valid, const int* __restrict__ seedp,
    u64* __restrict__ best) {
  __shared__ float mrow[16], srow[16];
  __shared__ u64 lbest[16];
  __shared__ int cnt;
  __shared__ u32 candk[4096];
  __shared__ float candv[4096];
  const int seg = blockIdx.x;  // 0..15
  const int tg = blockIdx.y;   // 0..63
  const int tid = threadIdx.x;
  const int w = tid >> 6, l = tid & 63, l15 = l & 15, g = l >> 4;
  const int b = tg >> 5;
  const int t0 = tg * 16;
  u32 kq0, kq1, km0, km1;
  derive_keys(seedp[0], kq0, kq1, km0, km1);
  if (tid < 16) {
    const float* cm = chunkmax + (size_t)(t0 + tid) * 64;
    const float* rp = rowsum_part + (size_t)(t0 + tid) * 64;
    float m = 0.f;
#pragma unroll
    for (int c = 0; c < 64; ++c) m = fmaxf(m, cm[c]);
    float s = 0.f;
#pragma unroll
    for (int c = 0; c < 64; ++c) s += rp[c];  // fixed order: deterministic
    mrow[tid] = m;
    srow[tid] = s * expf(-m);
    lbest[tid] = 0ull;
  }
  if (tid == 0) cnt = 0;
  const int n = derive_n(seedp[0], (u32)(t0 + l15));
  f16x8 q1, q2;
  load_split(f_q + ((size_t)b * NQ + n) * 32 + g * 4, q1, q2);
  const float et = expf(temp[0]);
  const float nv = num_valid[b];
  __syncthreads();
  const float th = mrow[l15] - 22.0f;

  for (int sc = 0; sc < 4; ++sc) {
#pragma unroll
    for (int i = 0; i < 4; ++i) {
      const int Tl = sc * 16 + w * 4 + i;  // tile within seg: 0..63
      const size_t moff = ((size_t)(b * 1024 + seg * 64 + Tl) * 64 + l) * 8;
      const f16x8 m1 = *(const f16x8*)(ms1 + moff);
      const f16x8 m2 = *(const f16x8*)(ms2 + moff);
      f32x4 r = emul_mfma(m1, m2, q1, q2);
#pragma unroll
      for (int j = 0; j < 4; ++j) {
        const float v = fmaxf(r[j], 0.f) * et;
        const bool pred = v > th;
        const u64 mask = __ballot(pred);
        if (mask) {  // one LDS atomic per wave per j (not per lane)
          const int leader = (int)(__ffsll((unsigned long long)mask) - 1);
          int wbase = 0;
          if (l == leader) wbase = atomicAdd(&cnt, (int)__popcll(mask));
          wbase = __shfl(wbase, leader, 64);
          if (pred) {
            const int pos =
                wbase + (int)__popcll(mask & ((1ull << l) - 1ull));
            candk[pos] = ((u32)l15 << 12) | (u32)(Tl * 16 + g * 4 + j);
            candv[pos] = v;
          }
        }
      }
    }
    __syncthreads();
    const int C = cnt;
    for (int c = tid; c < C; c += 256) {
      const u32 e = candk[c];
      const int r = (int)(e >> 12);
      const int f = seg * SEGW + (int)(e & 4095u);
      const float val = candv[c];
      const u32 wb = tf_xorbits(km0, km1, (u32)((t0 + r) * IJ + f));
      const float gmb = gumbel_from_bits(wb);
      const float v = logf((expf(val - mrow[r]) / srow[r]) / nv + 1e-20f) + gmb;
      const u64 key = ((u64)fkey(v) << 32) | (u64)(0xFFFFFFFFu - (u32)f);
      if (key > lbest[r]) atomicMax(&lbest[r], key);  // monotone: guard safe
    }
    __syncthreads();
    if (tid == 0) cnt = 0;
    __syncthreads();
  }
  if (tid < 16) atomicMax(&best[t0 + tid], lbest[tid]);
}

// ---------------- K3: pose (inline) + score, recompute sim on the fly ------
__global__ __launch_bounds__(256) void score_kernel(
    const float* __restrict__ f_q, const float* __restrict__ f_map,
    const float* __restrict__ q_xy, const void* __restrict__ valid_q,
    const void* __restrict__ valid_map, const float* __restrict__ num_valid,
    const float* __restrict__ temp, const u64* __restrict__ best,
    const int* __restrict__ seedp, const int* __restrict__ bool_is32,
    float* __restrict__ out) {
  __shared__ float sred[256];
  __shared__ float4 Psh;
  const int idx = blockIdx.x;  // b*256 + k
  const int tid = threadIdx.x;
  const int b = idx >> 8, k = idx & 255;
  if (tid == 0) {
    const int t0 = b * 512 + 2 * k, t1 = t0 + 1;
    const int na = derive_n(seedp[0], (u32)t0);
    const int nb = derive_n(seedp[0], (u32)t1);
    const float2 q0 = ((const float2*)q_xy)[(size_t)b * NQ + na];
    const float2 q1 = ((const float2*)q_xy)[(size_t)b * NQ + nb];
    const int ma = (int)(0xFFFFFFFFu - (u32)(best[t0] & 0xFFFFFFFFu));
    const int mb = (int)(0xFFFFFFFFu - (u32)(best[t1] & 0xFFFFFFFFu));
    const float m0x = ((float)(ma >> 7) + 0.5f) * 0.5f;
    const float m0y = ((float)(ma & 127) + 0.5f) * 0.5f;
    const float m1x = ((float)(mb >> 7) + 0.5f) * 0.5f;
    const float m1y = ((float)(mb & 127) + 0.5f) * 0.5f;
    const float dqx = q1.x - q0.x, dqy = q1.y - q0.y;
    const float dmx = m1x - m0x, dmy = m1y - m0y;
    const float theta = atan2f(dmy, dmx) - atan2f(dqy, dqx);
    const float c = cosf(theta), s = sinf(theta);
    const float tx = m0x - (c * q0.x - s * q0.y);
    const float ty = m0y - (s * q0.x + c * q0.y);
    Psh = make_float4(c, s, tx, ty);
  }
  __syncthreads();
  const float4 P = Psh;
  const int is32 = bool_is32[0];
  const float et = expf(temp[0]);
  float acc = 0.f;
  for (int n = tid; n < NQ; n += 256) {
    float2 q = ((const float2*)q_xy)[(size_t)b * NQ + n];
    float px = P.x * q.x - P.y * q.y + P.z;
    float py = P.y * q.x + P.x * q.y + P.w;
    int ii = (int)floorf(px * 2.0f);  // / CELL (=0.5) is exact *2
    int jj = (int)floorf(py * 2.0f);
    bool inb = (ii >= 0) & (ii < 128) & (jj >= 0) & (jj < 128);
    int ic = min(max(ii, 0), 127), jc = min(max(jj, 0), 127);
    int flat = (ic << 7) + jc;
    bool msk = read_bool(valid_q, b * NQ + n, is32) && inb &&
               read_bool(valid_map, b * IJ + flat, is32);
    if (msk) {
      const float4* A = (const float4*)(f_q + ((size_t)b * NQ + n) * 32);
      const float4* Bm = (const float4*)(f_map + ((size_t)b * IJ + flat) * 32);
      float4 s4 = {0.f, 0.f, 0.f, 0.f};
#pragma unroll
      for (int r = 0; r < 8; ++r) {
        float4 a = A[r], bb = Bm[r];
        s4.x = fmaf(a.x, bb.x, s4.x);
        s4.y = fmaf(a.y, bb.y, s4.y);
        s4.z = fmaf(a.z, bb.z, s4.z);
        s4.w = fmaf(a.w, bb.w, s4.w);
      }
      float dot = (s4.x + s4.y) + (s4.z + s4.w);
      acc += fmaxf(dot, 0.f) * et;
    }
  }
  sred[tid] = acc;
  __syncthreads();
  for (int off = 128; off > 0; off >>= 1) {
    if (tid < off) sred[tid] += sred[tid + off];
    __syncthreads();
  }
  if (tid == 0) out[idx] = sred[0] / num_valid[b];
}

// ---------------------------------------------------------------------------
extern "C" void kernel_launch(void* const* d_in, const int* in_sizes, int n_in,
                              void* d_out, int out_size, void* d_ws,
                              size_t ws_size, hipStream_t stream) {
  const float* f_q = (const float*)d_in[0];
  const float* f_map = (const float*)d_in[1];
  const float* q_xy = (const float*)d_in[2];
  const float* temp = (const float*)d_in[3];
  const void* valid_q = d_in[4];
  const void* valid_map = d_in[5];
  const int* seedp = (const int*)d_in[6];
  float* out = (float*)d_out;

  char* ws = (char*)d_ws;
  _Float16* ms1 = (_Float16*)ws;                 // 2 MB
  _Float16* ms2 = (_Float16*)(ws + 2097152);     // 2 MB
  float* chunkmax = (float*)(ws + 4194304);      // 256 KB
  float* rowsum_part = (float*)(ws + 4456448);   // 256 KB
  u64* best = (u64*)(ws + 4718592);              // 8 KB
  float* num_valid = (float*)(ws + 4726784);     // 8 B
  int* bool_is32 = (int*)(ws + 4726848);         // 4 B

  stats_kernel<<<dim3(64, 16), 256, 0, stream>>>(
      f_q, f_map, temp, valid_q, seedp, chunkmax, rowsum_part, best, num_valid,
      bool_is32, ms1, ms2);
  select_kernel<<<dim3(NSEG, 64), 256, 0, stream>>>(
      ms1, ms2, f_q, temp, chunkmax, rowsum_part, num_valid, seedp, best);
  score_kernel<<<NB * KP, 256, 0, stream>>>(f_q, f_map, q_xy, valid_q,
                                            valid_map, num_valid, temp, best,
                                            seedp, bool_is32, out);
}

// Round 5
// 137.479 us; speedup vs baseline: 1.0556x; 1.0556x over previous
//
#include <hip/hip_runtime.h>
#include <stdint.h>

typedef unsigned int u32;
typedef unsigned long long u64;
typedef _Float16 f16x8 __attribute__((ext_vector_type(8)));
typedef float f32x4 __attribute__((ext_vector_type(4)));

#define IJ 16384
#define NQ 1024
#define NB 2
#define KP 256
#define NSEG 16
#define SEGW 1024  // IJ / NSEG
#define NT 1024    // sampled rows (2 batches x 512)

// ---------------- Threefry-2x32 (JAX-compatible, 20 rounds) ----------------
__device__ __forceinline__ void tf2x32(u32 k0, u32 k1, u32& x0, u32& x1) {
  u32 kx = k0 ^ k1 ^ 0x1BD11BDAu;
#define TFR(r) { x0 += x1; x1 = (x1 << (r)) | (x1 >> (32 - (r))); x1 ^= x0; }
  x0 += k0; x1 += k1;
  TFR(13) TFR(15) TFR(26) TFR(6)
  x0 += k1; x1 += kx + 1u;
  TFR(17) TFR(29) TFR(16) TFR(24)
  x0 += kx; x1 += k0 + 2u;
  TFR(13) TFR(15) TFR(26) TFR(6)
  x0 += k0; x1 += k1 + 3u;
  TFR(17) TFR(29) TFR(16) TFR(24)
  x0 += k1; x1 += kx + 4u;
  TFR(13) TFR(15) TFR(26) TFR(6)
  x0 += kx; x1 += k0 + 5u;
#undef TFR
}

__device__ __forceinline__ void tf_subkey(u32 k0, u32 k1, u32 i, u32& s0, u32& s1) {
  u32 x0 = 0u, x1 = i;
  tf2x32(k0, k1, x0, x1);
  s0 = x0; s1 = x1;
}

__device__ __forceinline__ u32 tf_xorbits(u32 k0, u32 k1, u32 i) {
  u32 x0 = 0u, x1 = i;
  tf2x32(k0, k1, x0, x1);
  return x0 ^ x1;
}

__device__ __forceinline__ void derive_keys(int seed, u32& kq0, u32& kq1,
                                            u32& km0, u32& km1) {
  u32 k0 = 0u;
  u32 k1 = (u32)seed;
  tf_subkey(k0, k1, 0u, kq0, kq1);
  tf_subkey(k0, k1, 1u, km0, km1);
}

// n_idx[s] = random_bits(k2)[s] & 1023, k2 = split(kq)[1]
__device__ __forceinline__ int derive_n(int seed, u32 s) {
  u32 kq0, kq1, km0, km1;
  derive_keys(seed, kq0, kq1, km0, km1);
  u32 l0, l1;
  tf_subkey(kq0, kq1, 1u, l0, l1);
  return (int)(tf_xorbits(l0, l1, s) & 1023u);
}

__device__ __forceinline__ float gumbel_from_bits(u32 w) {
  const float tiny = 1.17549435e-38f;
  float fl = __uint_as_float((w >> 9) | 0x3f800000u) - 1.0f;
  float u = fl * (1.0f - tiny) + tiny;
  u = fmaxf(tiny, u);
  return -logf(-logf(u));
}

__device__ __forceinline__ bool read_bool(const void* p, int idx, int is32) {
  return is32 ? (((const int*)p)[idx] != 0)
              : (((const unsigned char*)p)[idx] != 0);
}

// monotone float<->u32 key (finite, non-NaN inputs)
__device__ __forceinline__ u32 fkey(float x) {
  u32 b = __float_as_uint(x);
  return b ^ ((b & 0x80000000u) ? 0xFFFFFFFFu : 0x80000000u);
}

// f32 -> (f16 hi, f16 lo*2^11) split, in-register (identical in both passes)
__device__ __forceinline__ void load_split(const float* __restrict__ src,
                                           f16x8& h1, f16x8& h2) {
  float4 a = *(const float4*)src;
  float4 b = *(const float4*)(src + 16);
  float x[8] = {a.x, a.y, a.z, a.w, b.x, b.y, b.z, b.w};
#pragma unroll
  for (int e = 0; e < 8; ++e) {
    _Float16 hi = (_Float16)x[e];
    h1[e] = hi;
    h2[e] = (_Float16)((x[e] - (float)hi) * 2048.0f);
  }
}

// fp32-emulated 16x16x32 via 4-MFMA Horner (error ~2^-21 per product)
__device__ __forceinline__ f32x4 emul_mfma(f16x8 m1, f16x8 m2, f16x8 q1,
                                           f16x8 q2) {
  const f32x4 zero4 = {0.f, 0.f, 0.f, 0.f};
  const float c11 = 4.8828125e-4f;  // 2^-11
  f32x4 x = __builtin_amdgcn_mfma_f32_16x16x32_f16(m2, q2, zero4, 0, 0, 0);
  x *= c11;
  x = __builtin_amdgcn_mfma_f32_16x16x32_f16(m2, q1, x, 0, 0, 0);
  x = __builtin_amdgcn_mfma_f32_16x16x32_f16(m1, q2, x, 0, 0, 0);
  x *= c11;
  return __builtin_amdgcn_mfma_f32_16x16x32_f16(m1, q1, x, 0, 0, 0);
}

// ---------------- K1: per-sampled-row chunk max + chunk sumexp -------------
// grid (64 ij-chunks, 16 row-groups); wave w owns rows [by*64+16w, +16).
// Plain stores (no init dependency); block (0,0) also does side jobs:
// best[] init, bool-width detect, num_valid.
__global__ __launch_bounds__(256) void stats_kernel(
    const float* __restrict__ f_q, const float* __restrict__ f_map,
    const float* __restrict__ temp, const void* __restrict__ valid_q,
    const int* __restrict__ seedp, float* __restrict__ chunkmax,
    float* __restrict__ rowsum_part, u64* __restrict__ best,
    float* __restrict__ num_valid, int* __restrict__ bool_is32) {
  __shared__ int sred[256];
  __shared__ int is32_s;
  const int bx = blockIdx.x;  // 256-ij chunk
  const int by = blockIdx.y;  // 64-row group
  const int tid = threadIdx.x;
  const int w = tid >> 6, l = tid & 63, l15 = l & 15, g = l >> 4;
  const int b = by >> 3;
  const int tp = by * 64 + w * 16 + l15;
  const int n = derive_n(seedp[0], (u32)tp);
  f16x8 q1, q2;
  load_split(f_q + ((size_t)b * NQ + n) * 32 + g * 4, q1, q2);
  const float et = expf(temp[0]);
  float rm = 0.f, se = 0.f;
#pragma unroll
  for (int T = 0; T < 16; ++T) {
    f16x8 m1, m2;
    load_split(f_map + ((size_t)b * IJ + (bx * 16 + T) * 16 + l15) * 32 + g * 4,
               m1, m2);
    f32x4 r = emul_mfma(m1, m2, q1, q2);
#pragma unroll
    for (int j = 0; j < 4; ++j) {
      float v = fmaxf(r[j], 0.f) * et;
      rm = fmaxf(rm, v);
      se += __expf(v);  // s only enters v as per-row log-shift: fast exp safe
    }
  }
  // deterministic reduce over the 4 lanes (g=0..3) holding the same row
  se += __shfl_xor(se, 16, 64);
  rm = fmaxf(rm, __shfl_xor(rm, 16, 64));
  se += __shfl_xor(se, 32, 64);
  rm = fmaxf(rm, __shfl_xor(rm, 32, 64));
  if (g == 0) {
    chunkmax[(size_t)tp * 64 + bx] = rm;
    rowsum_part[(size_t)tp * 64 + bx] = se;
  }
  if (bx == 0 && by == 0) {  // uniform per block: side jobs
    __syncthreads();
    for (int i = tid; i < NT; i += 256) best[i] = 0ull;  // fkey(-inf) floor
    const unsigned char* vb = (const unsigned char*)valid_q;
    int ones = 0;
    for (int i = tid; i < 2048; i += 256) ones += (vb[i] == 1) ? 1 : 0;
    sred[tid] = ones;
    __syncthreads();
    for (int off = 128; off > 0; off >>= 1) {
      if (tid < off) sred[tid] += sred[tid + off];
      __syncthreads();
    }
    if (tid == 0) {
      is32_s = (sred[0] < 1152) ? 1 : 0;
      bool_is32[0] = is32_s;
    }
    __syncthreads();
    const int is32 = is32_s;
    for (int bb = 0; bb < 2; ++bb) {
      int acc = 0;
      for (int i = tid; i < NQ; i += 256)
        acc += read_bool(valid_q, bb * NQ + i, is32) ? 1 : 0;
      sred[tid] = acc;
      __syncthreads();
      for (int off = 128; off > 0; off >>= 1) {
        if (tid < off) sred[tid] += sred[tid + off];
        __syncthreads();
      }
      if (tid == 0) {
        float nv = (float)sred[0];
        num_valid[bb] = nv < 1.f ? 1.f : nv;
      }
      __syncthreads();
    }
  }
}

// ---------------- K2: recompute + categorical argmax -----------------------
// Block = 16 sampled rows x SEGW ij. Recomputes sim bitwise == K1 (same
// loads, same split, same Horner). Per-block mrow/srow reduced in fixed order
// (bitwise == old sumexp_reduce). Candidates (val > m-22; winner bound
// m-21.11) compacted to LDS; exact R7 v; (max v, min f) via packed u64
// atomicMax (LDS then one global per row).
__global__ __launch_bounds__(256) void select_kernel(
    const float* __restrict__ f_q, const float* __restrict__ f_map,
    const float* __restrict__ temp, const float* __restrict__ chunkmax,
    const float* __restrict__ rowsum_part, const float* __restrict__ num_valid,
    const int* __restrict__ seedp, u64* __restrict__ best) {
  __shared__ float mrow[16], srow[16];
  __shared__ u64 lbest[16];
  __shared__ int cnt;
  __shared__ u32 candk[4096];
  __shared__ float candv[4096];
  const int seg = blockIdx.x;  // 0..15
  const int tg = blockIdx.y;   // 0..63
  const int tid = threadIdx.x;
  const int w = tid >> 6, l = tid & 63, l15 = l & 15, g = l >> 4;
  const int b = tg >> 5;
  const int t0 = tg * 16;
  u32 kq0, kq1, km0, km1;
  derive_keys(seedp[0], kq0, kq1, km0, km1);
  if (tid < 16) {
    const float* cm = chunkmax + (size_t)(t0 + tid) * 64;
    const float* rp = rowsum_part + (size_t)(t0 + tid) * 64;
    float m = 0.f;
#pragma unroll
    for (int c = 0; c < 64; ++c) m = fmaxf(m, cm[c]);
    float s = 0.f;
#pragma unroll
    for (int c = 0; c < 64; ++c) s += rp[c];  // fixed order: deterministic
    mrow[tid] = m;
    srow[tid] = s * expf(-m);
    lbest[tid] = 0ull;
  }
  if (tid == 0) cnt = 0;
  const int n = derive_n(seedp[0], (u32)(t0 + l15));
  f16x8 q1, q2;
  load_split(f_q + ((size_t)b * NQ + n) * 32 + g * 4, q1, q2);
  const float et = expf(temp[0]);
  const float nv = num_valid[b];
  __syncthreads();
  const float th = mrow[l15] - 22.0f;

  for (int sc = 0; sc < 4; ++sc) {
#pragma unroll
    for (int i = 0; i < 4; ++i) {
      const int Tl = sc * 16 + w * 4 + i;  // tile within seg: 0..63
      f16x8 m1, m2;
      load_split(
          f_map + ((size_t)b * IJ + seg * SEGW + Tl * 16 + l15) * 32 + g * 4,
          m1, m2);
      f32x4 r = emul_mfma(m1, m2, q1, q2);
#pragma unroll
      for (int j = 0; j < 4; ++j) {
        float v = fmaxf(r[j], 0.f) * et;
        if (v > th) {
          int p = atomicAdd(&cnt, 1);
          candk[p] = ((u32)l15 << 12) | (u32)(Tl * 16 + g * 4 + j);
          candv[p] = v;
        }
      }
    }
    __syncthreads();
    const int C = cnt;
    for (int c = tid; c < C; c += 256) {
      const u32 e = candk[c];
      const int r = (int)(e >> 12);
      const int f = seg * SEGW + (int)(e & 4095u);
      const float val = candv[c];
      const u32 wb = tf_xorbits(km0, km1, (u32)((t0 + r) * IJ + f));
      const float gmb = gumbel_from_bits(wb);
      const float v = logf((expf(val - mrow[r]) / srow[r]) / nv + 1e-20f) + gmb;
      const u64 key = ((u64)fkey(v) << 32) | (u64)(0xFFFFFFFFu - (u32)f);
      atomicMax(&lbest[r], key);
    }
    __syncthreads();
    if (tid == 0) cnt = 0;
    __syncthreads();
  }
  if (tid < 16) atomicMax(&best[t0 + tid], lbest[tid]);
}

// ---------------- K3: pose (inline) + score, recompute sim on the fly ------
__global__ __launch_bounds__(256) void score_kernel(
    const float* __restrict__ f_q, const float* __restrict__ f_map,
    const float* __restrict__ q_xy, const void* __restrict__ valid_q,
    const void* __restrict__ valid_map, const float* __restrict__ num_valid,
    const float* __restrict__ temp, const u64* __restrict__ best,
    const int* __restrict__ seedp, const int* __restrict__ bool_is32,
    float* __restrict__ out) {
  __shared__ float sred[256];
  __shared__ float4 Psh;
  const int idx = blockIdx.x;  // b*256 + k
  const int tid = threadIdx.x;
  const int b = idx >> 8, k = idx & 255;
  if (tid == 0) {
    const int t0 = b * 512 + 2 * k, t1 = t0 + 1;
    const int na = derive_n(seedp[0], (u32)t0);
    const int nb = derive_n(seedp[0], (u32)t1);
    const float2 q0 = ((const float2*)q_xy)[(size_t)b * NQ + na];
    const float2 q1 = ((const float2*)q_xy)[(size_t)b * NQ + nb];
    const int ma = (int)(0xFFFFFFFFu - (u32)(best[t0] & 0xFFFFFFFFu));
    const int mb = (int)(0xFFFFFFFFu - (u32)(best[t1] & 0xFFFFFFFFu));
    const float m0x = ((float)(ma >> 7) + 0.5f) * 0.5f;
    const float m0y = ((float)(ma & 127) + 0.5f) * 0.5f;
    const float m1x = ((float)(mb >> 7) + 0.5f) * 0.5f;
    const float m1y = ((float)(mb & 127) + 0.5f) * 0.5f;
    const float dqx = q1.x - q0.x, dqy = q1.y - q0.y;
    const float dmx = m1x - m0x, dmy = m1y - m0y;
    const float theta = atan2f(dmy, dmx) - atan2f(dqy, dqx);
    const float c = cosf(theta), s = sinf(theta);
    const float tx = m0x - (c * q0.x - s * q0.y);
    const float ty = m0y - (s * q0.x + c * q0.y);
    Psh = make_float4(c, s, tx, ty);
  }
  __syncthreads();
  const float4 P = Psh;
  const int is32 = bool_is32[0];
  const float et = expf(temp[0]);
  float acc = 0.f;
  for (int n = tid; n < NQ; n += 256) {
    float2 q = ((const float2*)q_xy)[(size_t)b * NQ + n];
    float px = P.x * q.x - P.y * q.y + P.z;
    float py = P.y * q.x + P.x * q.y + P.w;
    int ii = (int)floorf(px * 2.0f);  // / CELL (=0.5) is exact *2
    int jj = (int)floorf(py * 2.0f);
    bool inb = (ii >= 0) & (ii < 128) & (jj >= 0) & (jj < 128);
    int ic = min(max(ii, 0), 127), jc = min(max(jj, 0), 127);
    int flat = (ic << 7) + jc;
    bool msk = read_bool(valid_q, b * NQ + n, is32) && inb &&
               read_bool(valid_map, b * IJ + flat, is32);
    if (msk) {
      const float4* A = (const float4*)(f_q + ((size_t)b * NQ + n) * 32);
      const float4* Bm = (const float4*)(f_map + ((size_t)b * IJ + flat) * 32);
      float4 s4 = {0.f, 0.f, 0.f, 0.f};
#pragma unroll
      for (int r = 0; r < 8; ++r) {
        float4 a = A[r], bb = Bm[r];
        s4.x = fmaf(a.x, bb.x, s4.x);
        s4.y = fmaf(a.y, bb.y, s4.y);
        s4.z = fmaf(a.z, bb.z, s4.z);
        s4.w = fmaf(a.w, bb.w, s4.w);
      }
      float dot = (s4.x + s4.y) + (s4.z + s4.w);
      acc += fmaxf(dot, 0.f) * et;
    }
  }
  sred[tid] = acc;
  __syncthreads();
  for (int off = 128; off > 0; off >>= 1) {
    if (tid < off) sred[tid] += sred[tid + off];
    __syncthreads();
  }
  if (tid == 0) out[idx] = sred[0] / num_valid[b];
}

// ---------------------------------------------------------------------------
extern "C" void kernel_launch(void* const* d_in, const int* in_sizes, int n_in,
                              void* d_out, int out_size, void* d_ws,
                              size_t ws_size, hipStream_t stream) {
  const float* f_q = (const float*)d_in[0];
  const float* f_map = (const float*)d_in[1];
  const float* q_xy = (const float*)d_in[2];
  const float* temp = (const float*)d_in[3];
  const void* valid_q = d_in[4];
  const void* valid_map = d_in[5];
  const int* seedp = (const int*)d_in[6];
  float* out = (float*)d_out;

  char* ws = (char*)d_ws;
  float* chunkmax = (float*)ws;                  // 1024*64*4 = 256 KB
  float* rowsum_part = (float*)(ws + 262144);    // 256 KB
  u64* best = (u64*)(ws + 524288);               // 8 KB
  float* num_valid = (float*)(ws + 532480);      // 8 B
  int* bool_is32 = (int*)(ws + 532544);          // 4 B

  stats_kernel<<<dim3(64, 16), 256, 0, stream>>>(
      f_q, f_map, temp, valid_q, seedp, chunkmax, rowsum_part, best, num_valid,
      bool_is32);
  select_kernel<<<dim3(NSEG, 64), 256, 0, stream>>>(
      f_q, f_map, temp, chunkmax, rowsum_part, num_valid, seedp, best);
  score_kernel<<<NB * KP, 256, 0, stream>>>(f_q, f_map, q_xy, valid_q,
                                            valid_map, num_valid, temp, best,
                                            seedp, bool_is32, out);
}